// Round 16
// baseline (37.200 us; speedup 1.0000x reference)
//
#include <hip/hip_runtime.h>
#include <stdint.h>

typedef short bf16x8 __attribute__((ext_vector_type(8)));
typedef float f32x16 __attribute__((ext_vector_type(16)));
typedef float f32x4 __attribute__((ext_vector_type(4)));
typedef unsigned short ushort_t;

#define EMB 256
#define HID 1024
#define NTOK 16384

// ws: Wf column-interleaved fragment bf16 (512 KB) + Hs digest table (32 KB)
#define WS_W_OFF 0
#define WS_H_OFF (512u * 1024u)

// ---------------- SHA-256/224 primitives (proven R4-R15) ----------------
#define ROTR(x,n) (((x)>>(n))|((x)<<(32-(n))))
#define S0F(x) (ROTR((x),7)^ROTR((x),18)^((x)>>3))
#define S1F(x) (ROTR((x),17)^ROTR((x),19)^((x)>>10))

#define RND1(Kc, Wt) do {                                                          \
    uint32_t t1_ = sh + (ROTR(se,6)^ROTR(se,11)^ROTR(se,25))                       \
                   + ((se&sf)^(~se&sg)) + (Kc) + (Wt);                             \
    uint32_t t2_ = (ROTR(sa,2)^ROTR(sa,13)^ROTR(sa,22))                            \
                   + ((sa&sb)^(sa&sc)^(sb&sc));                                    \
    sh=sg; sg=sf; sf=se; se=sd+t1_; sd=sc; sc=sb; sb=sa; sa=t1_+t2_; } while (0)

#define WSXS(a,b,c,d) ((a) += S0F(b) + (c) + S1F(d))

__device__ __forceinline__ uint32_t rbf(float x) {
    uint32_t b = __float_as_uint(x);
    return (b + 0x7FFFu + ((b >> 16) & 1u)) >> 16;   // fp32 -> bf16 RNE
}
__device__ __forceinline__ uint4 pack8(float4 a, float4 b) {
    uint4 q;
    q.x = rbf(a.x) | (rbf(a.y) << 16);
    q.y = rbf(a.z) | (rbf(a.w) << 16);
    q.z = rbf(b.x) | (rbf(b.y) << 16);
    q.w = rbf(b.z) | (rbf(b.w) << 16);
    return q;
}

#define MFMA(av,bv,acc) __builtin_amdgcn_mfma_f32_32x32x16_bf16(av,bv,acc,0,0,0)

// Prepass (unchanged from R13/R14, proven): detect + ALL SHA digests ONCE ->
// Hs, plus W -> COLUMN-INTERLEAVED fragment bf16 Wf.
__global__ __launch_bounds__(128) void prep_kernel(const uint32_t* __restrict__ ids32,
                                                   const float* __restrict__ W,
                                                   ushort_t* __restrict__ Wf,
                                                   ushort_t* __restrict__ Hs) {
    __shared__ uint32_t redf[2];
    const int tid = (int)threadIdx.x;
    const int g = (int)blockIdx.x * 128 + tid;

    // ---- W loads issued early (8 floats) ----
    const int h = g >> 5, c8 = g & 31, kk = c8 >> 1, h8 = c8 & 1;
    const float4* wsrc = reinterpret_cast<const float4*>(W + h * EMB + kk * 16 + h8 * 8);
    float4 wa = wsrc[0], wb = wsrc[1];

    // ---- detect int64 vs int32 on the shared first 4KB ----
    {
        const uint4* ids4 = reinterpret_cast<const uint4*>(ids32);
        uint4 da = ids4[tid], db = ids4[tid + 128];
        uint32_t z = da.y | da.w | db.y | db.w;
        unsigned long long m = __ballot(z != 0u);
        if ((tid & 63) == 0) redf[tid >> 6] = (m != 0ull) ? 1u : 0u;
    }
    __syncthreads();
    const bool is64 = (redf[0] | redf[1]) == 0u;

    const int tok = g >> 1;
    const uint32_t st = g & 1;
    const uint32_t v = is64 ? ids32[2 * tok] : ids32[tok];

    // branchless decimal message
    const uint32_t q4 = __umulhi(v, 0xD1B71759u) >> 13;
    const uint32_t r4 = v - q4 * 10000u;
    const uint32_t q3 = __umulhi(r4, 0x10624DD3u) >> 6;
    const uint32_t r3 = r4 - q3 * 1000u;
    const uint32_t q2 = __umulhi(r3, 0x51EB851Fu) >> 5;
    const uint32_t r2 = r3 - q2 * 100u;
    const uint32_t q1 = __umulhi(r2, 0xCCCCCCCDu) >> 3;
    const uint32_t q0 = r2 - q1 * 10u;
    const uint32_t nd = v >= 10000u ? 5u : v >= 1000u ? 4u : v >= 100u ? 3u
                         : v >= 10u ? 2u : 1u;
    uint64_t M = ((uint64_t)(q4 + '0') << 56) | ((uint64_t)(q3 + '0') << 48) |
                 ((uint64_t)(q2 + '0') << 40) | ((uint64_t)(q1 + '0') << 32) |
                 ((uint64_t)(q0 + '0') << 24) | ((uint64_t)0x80u << 16);
    M <<= 8u * (5u - nd);

    uint32_t w0 = (uint32_t)(M >> 32), w1 = (uint32_t)M;
    uint32_t w2 = 0, w3 = 0, w4 = 0, w5 = 0, w6 = 0, w7 = 0;
    uint32_t w8 = 0, w9 = 0, w10 = 0, w11 = 0, w12 = 0, w13 = 0, w14 = 0;
    uint32_t w15 = nd * 8u;

    uint32_t sa = st ? 0xc1059ed8u : 0x6a09e667u;
    uint32_t sb = st ? 0x367cd507u : 0xbb67ae85u;
    uint32_t sc = st ? 0x3070dd17u : 0x3c6ef372u;
    uint32_t sd = st ? 0xf70e5939u : 0xa54ff53au;
    uint32_t se = st ? 0xffc00b31u : 0x510e527fu;
    uint32_t sf = st ? 0x68581511u : 0x9b05688cu;
    uint32_t sg = st ? 0x64f98fa7u : 0x1f83d9abu;
    uint32_t sh = st ? 0xbefa4fa4u : 0x5be0cd19u;

    // rounds 0-15
    RND1(0x428a2f98u, w0);  RND1(0x71374491u, w1);  RND1(0xb5c0fbcfu, w2);
    RND1(0xe9b5dba5u, w3);  RND1(0x3956c25bu, w4);  RND1(0x59f111f1u, w5);
    RND1(0x923f82a4u, w6);  RND1(0xab1c5ed5u, w7);  RND1(0xd807aa98u, w8);
    RND1(0x12835b01u, w9);  RND1(0x243185beu, w10); RND1(0x550c7dc3u, w11);
    RND1(0x72be5d74u, w12); RND1(0x80deb1feu, w13); RND1(0x9bdc06a7u, w14);
    RND1(0xc19bf174u, w15);
    // rounds 16-31
    WSXS(w0,w1,w9,w14);    RND1(0xe49b69c1u, w0);
    WSXS(w1,w2,w10,w15);   RND1(0xefbe4786u, w1);
    WSXS(w2,w3,w11,w0);    RND1(0x0fc19dc6u, w2);
    WSXS(w3,w4,w12,w1);    RND1(0x240ca1ccu, w3);
    WSXS(w4,w5,w13,w2);    RND1(0x2de92c6fu, w4);
    WSXS(w5,w6,w14,w3);    RND1(0x4a7484aau, w5);
    WSXS(w6,w7,w15,w4);    RND1(0x5cb0a9dcu, w6);
    WSXS(w7,w8,w0,w5);     RND1(0x76f988dau, w7);
    WSXS(w8,w9,w1,w6);     RND1(0x983e5152u, w8);
    WSXS(w9,w10,w2,w7);    RND1(0xa831c66du, w9);
    WSXS(w10,w11,w3,w8);   RND1(0xb00327c8u, w10);
    WSXS(w11,w12,w4,w9);   RND1(0xbf597fc7u, w11);
    WSXS(w12,w13,w5,w10);  RND1(0xc6e00bf3u, w12);
    WSXS(w13,w14,w6,w11);  RND1(0xd5a79147u, w13);
    WSXS(w14,w15,w7,w12);  RND1(0x06ca6351u, w14);
    WSXS(w15,w0,w8,w13);   RND1(0x14292967u, w15);
    // rounds 32-47
    WSXS(w0,w1,w9,w14);    RND1(0x27b70a85u, w0);
    WSXS(w1,w2,w10,w15);   RND1(0x2e1b2138u, w1);
    WSXS(w2,w3,w11,w0);    RND1(0x4d2c6dfcu, w2);
    WSXS(w3,w4,w12,w1);    RND1(0x53380d13u, w3);
    WSXS(w4,w5,w13,w2);    RND1(0x650a7354u, w4);
    WSXS(w5,w6,w14,w3);    RND1(0x766a0abbu, w5);
    WSXS(w6,w7,w15,w4);    RND1(0x81c2c92eu, w6);
    WSXS(w7,w8,w0,w5);     RND1(0x92722c85u, w7);
    WSXS(w8,w9,w1,w6);     RND1(0xa2bfe8a1u, w8);
    WSXS(w9,w10,w2,w7);    RND1(0xa81a664bu, w9);
    WSXS(w10,w11,w3,w8);   RND1(0xc24b8b70u, w10);
    WSXS(w11,w12,w4,w9);   RND1(0xc76c51a3u, w11);
    WSXS(w12,w13,w5,w10);  RND1(0xd192e819u, w12);
    WSXS(w13,w14,w6,w11);  RND1(0xd6990624u, w13);
    WSXS(w14,w15,w7,w12);  RND1(0xf40e3585u, w14);
    WSXS(w15,w0,w8,w13);   RND1(0x106aa070u, w15);
    // rounds 48-63
    WSXS(w0,w1,w9,w14);    RND1(0x19a4c116u, w0);
    WSXS(w1,w2,w10,w15);   RND1(0x1e376c08u, w1);
    WSXS(w2,w3,w11,w0);    RND1(0x2748774cu, w2);
    WSXS(w3,w4,w12,w1);    RND1(0x34b0bcb5u, w3);
    WSXS(w4,w5,w13,w2);    RND1(0x391c0cb3u, w4);
    WSXS(w5,w6,w14,w3);    RND1(0x4ed8aa4au, w5);
    WSXS(w6,w7,w15,w4);    RND1(0x5b9cca4fu, w6);
    WSXS(w7,w8,w0,w5);     RND1(0x682e6ff3u, w7);
    WSXS(w8,w9,w1,w6);     RND1(0x748f82eeu, w8);
    WSXS(w9,w10,w2,w7);    RND1(0x78a5636fu, w9);
    WSXS(w10,w11,w3,w8);   RND1(0x84c87814u, w10);
    WSXS(w11,w12,w4,w9);   RND1(0x8cc70208u, w11);
    WSXS(w12,w13,w5,w10);  RND1(0x90befffau, w12);
    WSXS(w13,w14,w6,w11);  RND1(0xa4506cebu, w13);
    WSXS(w14,w15,w7,w12);  RND1(0xbef9a3f7u, w14);
    WSXS(w15,w0,w8,w13);   RND1(0xc67178f2u, w15);

    const uint32_t hv = ((st ? 0xc1059ed8u : 0x6a09e667u) + sa) >> 24;
    const uint32_t hvo = __shfl_xor(hv, 1);          // partner's digest byte
    if (st == 0) Hs[tok] = (ushort_t)(hv | (hvo << 8));   // h1 | h2<<8

    // ---- W chunk -> column-interleaved Wf fragment (R12/R13-proven) ----
    const int P = h >> 7, hl = h & 127, j = hl & 3, cc = hl >> 2;
    uint4* wbase = reinterpret_cast<uint4*>(Wf)
                   + ((size_t)(P * 4 + j) * 16 + kk) * 64 + cc + h8 * 32;
    *wbase = pack8(wa, wb);
}

// Fused GEMM, 2-round pipeline: block = 32 tokens x ALL 1024 cols (128KB
// contiguous output), grid 512 -> 2 blocks/CU -> block A's store DRAIN
// overlaps block B's A-regen+MFMA (the untested mechanism: with 1 block/CU
// the end-of-kernel store drain had nothing to overlap). Plain float4 stores
// (R14-proven; NT regressed in R15). Wave = 32 tok x 128 col, 4 accs.
__global__ __launch_bounds__(512, 4) void fused_kernel(const ushort_t* __restrict__ Hs,
                                                       const ushort_t* __restrict__ Wf,
                                                       const float* __restrict__ bias,
                                                       float* __restrict__ out) {
    __shared__ uint4 Albuf[1024];   // A: [16 kf][64 lane] x 16B = 16KB

    const int bm = (int)blockIdx.x;          // 32-token tile, all columns
    const int tid = (int)threadIdx.x;
    const int wv = tid >> 6, lane = tid & 63, lrow = lane & 31, lh = lane >> 5;

    // ---- A fragments from Hs: 16 threads per token, 1 kf each ----
    {
        const int tk = tid >> 4;             // local token 0..31
        const int kf = tid & 15;
        const uint32_t hsv = Hs[bm * 32 + tk];
        const uint32_t hv1 = hsv & 255u, hv2 = hsv >> 8;
        const uint32_t kstart = (uint32_t)kf * 16u;
        uint32_t val = (hv1 + hv2 * kstart) & 255u;
#define PAIR(dst) { uint32_t lo_ = val; uint32_t hi_ = (val + hv2) & 255u;        \
                    val = (hi_ + hv2) & 255u;                                     \
                    dst = (__float_as_uint((float)lo_) >> 16) |                   \
                          (__float_as_uint((float)hi_) & 0xFFFF0000u); }
        uint32_t c0_, c1_, c2_, c3_, c4_, c5_, c6_, c7_;
        PAIR(c0_); PAIR(c1_); PAIR(c2_); PAIR(c3_);
        PAIR(c4_); PAIR(c5_); PAIR(c6_); PAIR(c7_);
#undef PAIR
        uint4 qa; qa.x = c0_; qa.y = c1_; qa.z = c2_; qa.w = c3_;
        uint4 qb; qb.x = c4_; qb.y = c5_; qb.z = c6_; qb.w = c7_;
        Albuf[kf * 64 + tk]      = qa;   // k-half 0 (lh=0 lanes)
        Albuf[kf * 64 + tk + 32] = qb;   // k-half 1 (lh=1 lanes)
    }

    // wave's 128-col panel and its interleaved bias float4
    const int C0 = wv * 128;
    const f32x4 b4 = *reinterpret_cast<const f32x4*>(bias + C0 + 4 * lrow);

    __syncthreads();    // A complete; no more barriers

    const bf16x8* bfr = reinterpret_cast<const bf16x8*>(Wf);
    const bf16x8* alr = reinterpret_cast<const bf16x8*>(Albuf);
    const int gb0 = wv * 4;                  // 4 interleave-class B-groups

    f32x16 A00 = (f32x16)(0.0f), A01 = (f32x16)(0.0f);
    f32x16 A02 = (f32x16)(0.0f), A03 = (f32x16)(0.0f);

#pragma unroll 2
    for (int kf = 0; kf < 16; ++kf) {
        bf16x8 av  = alr[kf * 64 + lane];            // tokens 0-31
        bf16x8 bv0 = bfr[((size_t)((gb0 + 0) * 16 + kf)) * 64 + lane];
        bf16x8 bv1 = bfr[((size_t)((gb0 + 1) * 16 + kf)) * 64 + lane];
        bf16x8 bv2 = bfr[((size_t)((gb0 + 2) * 16 + kf)) * 64 + lane];
        bf16x8 bv3 = bfr[((size_t)((gb0 + 3) * 16 + kf)) * 64 + lane];
        A00 = MFMA(av, bv0, A00); A01 = MFMA(av, bv1, A01);
        A02 = MFMA(av, bv2, A02); A03 = MFMA(av, bv3, A03);
    }

    // epilogue: plain float4 stores; block output = 128KB contiguous
    const int m0 = bm * 32;
    float* obase = out + (size_t)C0 + 4 * lrow;
#pragma unroll
    for (int r = 0; r < 16; ++r) {
        const int rowl = (r & 3) + 8 * (r >> 2) + 4 * lh;  // verified C/D layout
        f32x4 v0;
        v0[0] = A00[r] + b4[0]; v0[1] = A01[r] + b4[1];
        v0[2] = A02[r] + b4[2]; v0[3] = A03[r] + b4[3];
        *reinterpret_cast<f32x4*>(obase + (size_t)(m0 + rowl) * HID) = v0;
    }
}

extern "C" void kernel_launch(void* const* d_in, const int* in_sizes, int n_in,
                              void* d_out, int out_size, void* d_ws, size_t ws_size,
                              hipStream_t stream) {
    const uint32_t* ids32 = (const uint32_t*)d_in[0];
    const float* W = (const float*)d_in[1];
    const float* bias = (const float*)d_in[2];
    float* out = (float*)d_out;
    ushort_t* Wf = (ushort_t*)((char*)d_ws + WS_W_OFF);
    ushort_t* Hs = (ushort_t*)((char*)d_ws + WS_H_OFF);
    (void)in_sizes; (void)n_in; (void)out_size; (void)ws_size;

    prep_kernel<<<256, 128, 0, stream>>>(ids32, W, Wf, Hs);
    fused_kernel<<<512, 512, 0, stream>>>(Hs, Wf, bias, out);
}

// Round 17
// 32.677 us; speedup vs baseline: 1.1384x; 1.1384x over previous
//
#include <hip/hip_runtime.h>
#include <stdint.h>

typedef short bf16x8 __attribute__((ext_vector_type(8)));
typedef float f32x16 __attribute__((ext_vector_type(16)));
typedef float f32x4 __attribute__((ext_vector_type(4)));
typedef unsigned short ushort_t;

#define EMB 256
#define HID 1024
#define NTOK 16384

// ws: Wf column-interleaved fragment bf16 (512 KB) + Hs digest table (32 KB)
#define WS_W_OFF 0
#define WS_H_OFF (512u * 1024u)

// ---------------- SHA-256/224 primitives (proven R4-R16) ----------------
#define ROTR(x,n) (((x)>>(n))|((x)<<(32-(n))))
#define S0F(x) (ROTR((x),7)^ROTR((x),18)^((x)>>3))
#define S1F(x) (ROTR((x),17)^ROTR((x),19)^((x)>>10))

#define RND1(Kc, Wt) do {                                                          \
    uint32_t t1_ = sh + (ROTR(se,6)^ROTR(se,11)^ROTR(se,25))                       \
                   + ((se&sf)^(~se&sg)) + (Kc) + (Wt);                             \
    uint32_t t2_ = (ROTR(sa,2)^ROTR(sa,13)^ROTR(sa,22))                            \
                   + ((sa&sb)^(sa&sc)^(sb&sc));                                    \
    sh=sg; sg=sf; sf=se; se=sd+t1_; sd=sc; sc=sb; sb=sa; sa=t1_+t2_; } while (0)

#define WSXS(a,b,c,d) ((a) += S0F(b) + (c) + S1F(d))

__device__ __forceinline__ uint32_t rbf(float x) {
    uint32_t b = __float_as_uint(x);
    return (b + 0x7FFFu + ((b >> 16) & 1u)) >> 16;   // fp32 -> bf16 RNE
}
__device__ __forceinline__ uint4 pack8(float4 a, float4 b) {
    uint4 q;
    q.x = rbf(a.x) | (rbf(a.y) << 16);
    q.y = rbf(a.z) | (rbf(a.w) << 16);
    q.z = rbf(b.x) | (rbf(b.y) << 16);
    q.w = rbf(b.z) | (rbf(b.w) << 16);
    return q;
}

#define MFMA(av,bv,acc) __builtin_amdgcn_mfma_f32_32x32x16_bf16(av,bv,acc,0,0,0)

// Prepass (proven R13/R14): detect + ALL SHA digests ONCE -> Hs, plus
// W -> COLUMN-INTERLEAVED fragment bf16 Wf.
__global__ __launch_bounds__(128) void prep_kernel(const uint32_t* __restrict__ ids32,
                                                   const float* __restrict__ W,
                                                   ushort_t* __restrict__ Wf,
                                                   ushort_t* __restrict__ Hs) {
    __shared__ uint32_t redf[2];
    const int tid = (int)threadIdx.x;
    const int g = (int)blockIdx.x * 128 + tid;

    // ---- W loads issued early (8 floats) ----
    const int h = g >> 5, c8 = g & 31, kk = c8 >> 1, h8 = c8 & 1;
    const float4* wsrc = reinterpret_cast<const float4*>(W + h * EMB + kk * 16 + h8 * 8);
    float4 wa = wsrc[0], wb = wsrc[1];

    // ---- detect int64 vs int32 on the shared first 4KB ----
    {
        const uint4* ids4 = reinterpret_cast<const uint4*>(ids32);
        uint4 da = ids4[tid], db = ids4[tid + 128];
        uint32_t z = da.y | da.w | db.y | db.w;
        unsigned long long m = __ballot(z != 0u);
        if ((tid & 63) == 0) redf[tid >> 6] = (m != 0ull) ? 1u : 0u;
    }
    __syncthreads();
    const bool is64 = (redf[0] | redf[1]) == 0u;

    const int tok = g >> 1;
    const uint32_t st = g & 1;
    const uint32_t v = is64 ? ids32[2 * tok] : ids32[tok];

    // branchless decimal message
    const uint32_t q4 = __umulhi(v, 0xD1B71759u) >> 13;
    const uint32_t r4 = v - q4 * 10000u;
    const uint32_t q3 = __umulhi(r4, 0x10624DD3u) >> 6;
    const uint32_t r3 = r4 - q3 * 1000u;
    const uint32_t q2 = __umulhi(r3, 0x51EB851Fu) >> 5;
    const uint32_t r2 = r3 - q2 * 100u;
    const uint32_t q1 = __umulhi(r2, 0xCCCCCCCDu) >> 3;
    const uint32_t q0 = r2 - q1 * 10u;
    const uint32_t nd = v >= 10000u ? 5u : v >= 1000u ? 4u : v >= 100u ? 3u
                         : v >= 10u ? 2u : 1u;
    uint64_t M = ((uint64_t)(q4 + '0') << 56) | ((uint64_t)(q3 + '0') << 48) |
                 ((uint64_t)(q2 + '0') << 40) | ((uint64_t)(q1 + '0') << 32) |
                 ((uint64_t)(q0 + '0') << 24) | ((uint64_t)0x80u << 16);
    M <<= 8u * (5u - nd);

    uint32_t w0 = (uint32_t)(M >> 32), w1 = (uint32_t)M;
    uint32_t w2 = 0, w3 = 0, w4 = 0, w5 = 0, w6 = 0, w7 = 0;
    uint32_t w8 = 0, w9 = 0, w10 = 0, w11 = 0, w12 = 0, w13 = 0, w14 = 0;
    uint32_t w15 = nd * 8u;

    uint32_t sa = st ? 0xc1059ed8u : 0x6a09e667u;
    uint32_t sb = st ? 0x367cd507u : 0xbb67ae85u;
    uint32_t sc = st ? 0x3070dd17u : 0x3c6ef372u;
    uint32_t sd = st ? 0xf70e5939u : 0xa54ff53au;
    uint32_t se = st ? 0xffc00b31u : 0x510e527fu;
    uint32_t sf = st ? 0x68581511u : 0x9b05688cu;
    uint32_t sg = st ? 0x64f98fa7u : 0x1f83d9abu;
    uint32_t sh = st ? 0xbefa4fa4u : 0x5be0cd19u;

    // rounds 0-15
    RND1(0x428a2f98u, w0);  RND1(0x71374491u, w1);  RND1(0xb5c0fbcfu, w2);
    RND1(0xe9b5dba5u, w3);  RND1(0x3956c25bu, w4);  RND1(0x59f111f1u, w5);
    RND1(0x923f82a4u, w6);  RND1(0xab1c5ed5u, w7);  RND1(0xd807aa98u, w8);
    RND1(0x12835b01u, w9);  RND1(0x243185beu, w10); RND1(0x550c7dc3u, w11);
    RND1(0x72be5d74u, w12); RND1(0x80deb1feu, w13); RND1(0x9bdc06a7u, w14);
    RND1(0xc19bf174u, w15);
    // rounds 16-31
    WSXS(w0,w1,w9,w14);    RND1(0xe49b69c1u, w0);
    WSXS(w1,w2,w10,w15);   RND1(0xefbe4786u, w1);
    WSXS(w2,w3,w11,w0);    RND1(0x0fc19dc6u, w2);
    WSXS(w3,w4,w12,w1);    RND1(0x240ca1ccu, w3);
    WSXS(w4,w5,w13,w2);    RND1(0x2de92c6fu, w4);
    WSXS(w5,w6,w14,w3);    RND1(0x4a7484aau, w5);
    WSXS(w6,w7,w15,w4);    RND1(0x5cb0a9dcu, w6);
    WSXS(w7,w8,w0,w5);     RND1(0x76f988dau, w7);
    WSXS(w8,w9,w1,w6);     RND1(0x983e5152u, w8);
    WSXS(w9,w10,w2,w7);    RND1(0xa831c66du, w9);
    WSXS(w10,w11,w3,w8);   RND1(0xb00327c8u, w10);
    WSXS(w11,w12,w4,w9);   RND1(0xbf597fc7u, w11);
    WSXS(w12,w13,w5,w10);  RND1(0xc6e00bf3u, w12);
    WSXS(w13,w14,w6,w11);  RND1(0xd5a79147u, w13);
    WSXS(w14,w15,w7,w12);  RND1(0x06ca6351u, w14);
    WSXS(w15,w0,w8,w13);   RND1(0x14292967u, w15);
    // rounds 32-47
    WSXS(w0,w1,w9,w14);    RND1(0x27b70a85u, w0);
    WSXS(w1,w2,w10,w15);   RND1(0x2e1b2138u, w1);
    WSXS(w2,w3,w11,w0);    RND1(0x4d2c6dfcu, w2);
    WSXS(w3,w4,w12,w1);    RND1(0x53380d13u, w3);
    WSXS(w4,w5,w13,w2);    RND1(0x650a7354u, w4);
    WSXS(w5,w6,w14,w3);    RND1(0x766a0abbu, w5);
    WSXS(w6,w7,w15,w4);    RND1(0x81c2c92eu, w6);
    WSXS(w7,w8,w0,w5);     RND1(0x92722c85u, w7);
    WSXS(w8,w9,w1,w6);     RND1(0xa2bfe8a1u, w8);
    WSXS(w9,w10,w2,w7);    RND1(0xa81a664bu, w9);
    WSXS(w10,w11,w3,w8);   RND1(0xc24b8b70u, w10);
    WSXS(w11,w12,w4,w9);   RND1(0xc76c51a3u, w11);
    WSXS(w12,w13,w5,w10);  RND1(0xd192e819u, w12);
    WSXS(w13,w14,w6,w11);  RND1(0xd6990624u, w13);
    WSXS(w14,w15,w7,w12);  RND1(0xf40e3585u, w14);
    WSXS(w15,w0,w8,w13);   RND1(0x106aa070u, w15);
    // rounds 48-63
    WSXS(w0,w1,w9,w14);    RND1(0x19a4c116u, w0);
    WSXS(w1,w2,w10,w15);   RND1(0x1e376c08u, w1);
    WSXS(w2,w3,w11,w0);    RND1(0x2748774cu, w2);
    WSXS(w3,w4,w12,w1);    RND1(0x34b0bcb5u, w3);
    WSXS(w4,w5,w13,w2);    RND1(0x391c0cb3u, w4);
    WSXS(w5,w6,w14,w3);    RND1(0x4ed8aa4au, w5);
    WSXS(w6,w7,w15,w4);    RND1(0x5b9cca4fu, w6);
    WSXS(w7,w8,w0,w5);     RND1(0x682e6ff3u, w7);
    WSXS(w8,w9,w1,w6);     RND1(0x748f82eeu, w8);
    WSXS(w9,w10,w2,w7);    RND1(0x78a5636fu, w9);
    WSXS(w10,w11,w3,w8);   RND1(0x84c87814u, w10);
    WSXS(w11,w12,w4,w9);   RND1(0x8cc70208u, w11);
    WSXS(w12,w13,w5,w10);  RND1(0x90befffau, w12);
    WSXS(w13,w14,w6,w11);  RND1(0xa4506cebu, w13);
    WSXS(w14,w15,w7,w12);  RND1(0xbef9a3f7u, w14);
    WSXS(w15,w0,w8,w13);   RND1(0xc67178f2u, w15);

    const uint32_t hv = ((st ? 0xc1059ed8u : 0x6a09e667u) + sa) >> 24;
    const uint32_t hvo = __shfl_xor(hv, 1);          // partner's digest byte
    if (st == 0) Hs[tok] = (ushort_t)(hv | (hvo << 8));   // h1 | h2<<8

    // ---- W chunk -> column-interleaved Wf fragment (R12/R13-proven) ----
    const int P = h >> 7, hl = h & 127, j = hl & 3, cc = hl >> 2;
    uint4* wbase = reinterpret_cast<uint4*>(Wf)
                   + ((size_t)(P * 4 + j) * 16 + kk) * 64 + cc + h8 * 32;
    *wbase = pack8(wa, wb);
}

// Fused GEMM (R14 best configuration, 32.68us): block = 64 tokens x ALL 1024
// cols -> one linear 256KB output span; A regenerated from Hs into 32KB LDS
// (one barrier); B from L2-hot interleaved Wf, disjoint per wave; plain
// float4 stores. Grid 256 x 512 thr (8 waves, 1 block/CU).
__global__ __launch_bounds__(512, 2) void fused_kernel(const ushort_t* __restrict__ Hs,
                                                       const ushort_t* __restrict__ Wf,
                                                       const float* __restrict__ bias,
                                                       float* __restrict__ out) {
    __shared__ uint4 Albuf[2048];   // A: [2 ag][16 kf][64 lane] x 16B = 32KB

    const int bm = (int)blockIdx.x;          // 64-token tile, all columns
    const int tid = (int)threadIdx.x;
    const int wv = tid >> 6, lane = tid & 63, lrow = lane & 31, lh = lane >> 5;

    // ---- A fragments from Hs: 8 threads per token (tok = tid>>3) ----
    {
        const int tk = tid >> 3;             // local token 0..63
        const int sub = tid & 7;
        const uint32_t st = (uint32_t)(sub >> 2);   // k-half-of-256 (0/1)
        const int qh = sub & 3;              // quarter within half
        const uint32_t hsv = Hs[bm * 64 + tk];
        const uint32_t hv1 = hsv & 255u, hv2 = hsv >> 8;
        const int ag = tk >> 5, aslot = tk & 31;
        const uint32_t kstart = st * 128u + (uint32_t)qh * 32u;
        uint32_t val = (hv1 + hv2 * kstart) & 255u;
        const int kf0 = (int)st * 8 + qh * 2;
#define PAIR(dst) { uint32_t lo_ = val; uint32_t hi_ = (val + hv2) & 255u;        \
                    val = (hi_ + hv2) & 255u;                                     \
                    dst = (__float_as_uint((float)lo_) >> 16) |                   \
                          (__float_as_uint((float)hi_) & 0xFFFF0000u); }
#pragma unroll
        for (int q = 0; q < 2; ++q) {
            uint32_t c0_, c1_, c2_, c3_, c4_, c5_, c6_, c7_;
            PAIR(c0_); PAIR(c1_); PAIR(c2_); PAIR(c3_);
            PAIR(c4_); PAIR(c5_); PAIR(c6_); PAIR(c7_);
            uint4 qa; qa.x = c0_; qa.y = c1_; qa.z = c2_; qa.w = c3_;
            uint4 qb; qb.x = c4_; qb.y = c5_; qb.z = c6_; qb.w = c7_;
            Albuf[(ag * 16 + kf0 + q) * 64 + aslot]      = qa;   // k-half 0
            Albuf[(ag * 16 + kf0 + q) * 64 + aslot + 32] = qb;   // k-half 1
        }
#undef PAIR
    }

    // wave's 128-col panel and its interleaved bias float4
    const int C0 = wv * 128;
    const f32x4 b4 = *reinterpret_cast<const f32x4*>(bias + C0 + 4 * lrow);

    __syncthreads();    // A complete; no more barriers

    const bf16x8* bfr = reinterpret_cast<const bf16x8*>(Wf);
    const bf16x8* alr = reinterpret_cast<const bf16x8*>(Albuf);
    const int gb0 = wv * 4;                  // 4 interleave-class B-groups

    f32x16 A00 = (f32x16)(0.0f), A01 = (f32x16)(0.0f);
    f32x16 A02 = (f32x16)(0.0f), A03 = (f32x16)(0.0f);
    f32x16 A10 = (f32x16)(0.0f), A11 = (f32x16)(0.0f);
    f32x16 A12 = (f32x16)(0.0f), A13 = (f32x16)(0.0f);

#pragma unroll 2
    for (int kf = 0; kf < 16; ++kf) {
        bf16x8 av0 = alr[kf * 64 + lane];            // tokens 0-31
        bf16x8 av1 = alr[(16 + kf) * 64 + lane];     // tokens 32-63
        bf16x8 bv0 = bfr[((size_t)((gb0 + 0) * 16 + kf)) * 64 + lane];
        bf16x8 bv1 = bfr[((size_t)((gb0 + 1) * 16 + kf)) * 64 + lane];
        bf16x8 bv2 = bfr[((size_t)((gb0 + 2) * 16 + kf)) * 64 + lane];
        bf16x8 bv3 = bfr[((size_t)((gb0 + 3) * 16 + kf)) * 64 + lane];
        A00 = MFMA(av0, bv0, A00); A01 = MFMA(av0, bv1, A01);
        A02 = MFMA(av0, bv2, A02); A03 = MFMA(av0, bv3, A03);
        A10 = MFMA(av1, bv0, A10); A11 = MFMA(av1, bv1, A11);
        A12 = MFMA(av1, bv2, A12); A13 = MFMA(av1, bv3, A13);
    }

    // epilogue: lane owns cols C0+4*lrow..+3; block output = 256KB contiguous
    const int m0 = bm * 64;
    float* obase = out + (size_t)C0 + 4 * lrow;
#pragma unroll
    for (int r = 0; r < 16; ++r) {
        const int rowl = (r & 3) + 8 * (r >> 2) + 4 * lh;  // verified C/D layout
        f32x4 v0, v1;
        v0[0] = A00[r] + b4[0]; v0[1] = A01[r] + b4[1];
        v0[2] = A02[r] + b4[2]; v0[3] = A03[r] + b4[3];
        v1[0] = A10[r] + b4[0]; v1[1] = A11[r] + b4[1];
        v1[2] = A12[r] + b4[2]; v1[3] = A13[r] + b4[3];
        *reinterpret_cast<f32x4*>(obase + (size_t)(m0 + rowl) * HID)      = v0;
        *reinterpret_cast<f32x4*>(obase + (size_t)(m0 + 32 + rowl) * HID) = v1;
    }
}

extern "C" void kernel_launch(void* const* d_in, const int* in_sizes, int n_in,
                              void* d_out, int out_size, void* d_ws, size_t ws_size,
                              hipStream_t stream) {
    const uint32_t* ids32 = (const uint32_t*)d_in[0];
    const float* W = (const float*)d_in[1];
    const float* bias = (const float*)d_in[2];
    float* out = (float*)d_out;
    ushort_t* Wf = (ushort_t*)((char*)d_ws + WS_W_OFF);
    ushort_t* Hs = (ushort_t*)((char*)d_ws + WS_H_OFF);
    (void)in_sizes; (void)n_in; (void)out_size; (void)ws_size;

    prep_kernel<<<256, 128, 0, stream>>>(ids32, W, Wf, Hs);
    fused_kernel<<<256, 512, 0, stream>>>(Hs, Wf, bias, out);
}